// Round 10
// baseline (283.354 us; speedup 1.0000x reference)
//
#include <hip/hip_runtime.h>
#include <cmath>

namespace {

constexpr int BATCH = 256;
// layer 1
constexpr int C1 = 3, H1 = 218, W1 = 178;
constexpr int IMG1 = C1 * H1 * W1;            // 116412
constexpr int PLANE1 = H1 * W1;               // 38804
constexpr int O1 = 8, HO1 = 54, WO1 = 44;
constexpr int HW1 = HO1 * WO1;                // 2376
constexpr int P1 = C1 * 36;                   // 108
// layer 2
constexpr int C2 = 8, H2c = 54, W2c = 44;
constexpr int IMG2 = C2 * H2c * W2c;          // 19008
constexpr int PLANE2 = H2c * W2c;             // 2376
constexpr int O2 = 16, HO2 = 13, WO2 = 10;
constexpr int HW2 = HO2 * WO2;                // 130
constexpr int P2 = C2 * 36;                   // 288
// head
constexpr int NPOOL = 480;                    // 16*6*5
constexpr int N1 = 300, N2 = 200;

// lc1: 512 thr = 8 waves x 64 hw-lanes; wave = 4 batches -> NB=32/block.
// Rationale (r3/r7/r9 evidence): per-CU bytes-through-L1 throughput is
// ~10-15 GB/s in every config; time == bytes/CU / rate. At NB=16..8 the
// w1t stream is re-pulled 16-32x (131-262 MB). NB=32 cuts w to 66 MB.
constexpr int BJ1 = 4;
constexpr int NB1 = 32;                       // 8 waves * BJ1

// ---- transpose w1 (O1,P1,HW1) -> (P1*HW1, O1)
__global__ __launch_bounds__(256) void wt1_kernel(const float* __restrict__ w,
                                                  float* __restrict__ wt) {
  const int idx = blockIdx.x * 256 + threadIdx.x;   // p*HW1 + hw
  if (idx >= P1 * HW1) return;
  float v[O1];
#pragma unroll
  for (int o = 0; o < O1; ++o) v[o] = w[(size_t)o * (P1 * HW1) + idx];
  float4* dst = reinterpret_cast<float4*>(wt + (size_t)idx * O1);
  dst[0] = make_float4(v[0], v[1], v[2], v[3]);
  dst[1] = make_float4(v[4], v[5], v[6], v[7]);
}

// ---- transpose w2 (O2,P2,HW2) -> (P2*HW2, O2)
__global__ __launch_bounds__(256) void wt2_kernel(const float* __restrict__ w,
                                                  float* __restrict__ wt) {
  const int idx = blockIdx.x * 256 + threadIdx.x;   // p*HW2 + hw
  if (idx >= P2 * HW2) return;
  float v[O2];
#pragma unroll
  for (int o = 0; o < O2; ++o) v[o] = w[(size_t)o * (P2 * HW2) + idx];
  float4* dst = reinterpret_cast<float4*>(wt + (size_t)idx * O2);
  dst[0] = make_float4(v[0], v[1], v[2], v[3]);
  dst[1] = make_float4(v[4], v[5], v[6], v[7]);
  dst[2] = make_float4(v[8], v[9], v[10], v[11]);
  dst[3] = make_float4(v[12], v[13], v[14], v[15]);
}

// ---- locally-connected layer 1 + ReLU. Direct dense loads, NB=32,
// cross-chunk register double-buffer (A/B) with sched fences.
__global__ __launch_bounds__(512) void lc1_kernel(const float* __restrict__ x,
                                                  const float* __restrict__ w1t,
                                                  const float* __restrict__ b1,
                                                  float* __restrict__ h1) {
  const int lane = threadIdx.x & 63;
  const int wave = threadIdx.x >> 6;
  const int hw = blockIdx.x * 64 + lane;
  if (hw >= HW1) return;
  const int bg = blockIdx.y * NB1 + wave * BJ1;
  const int ho = hw / WO1, wo = hw - ho * WO1;

  float acc[BJ1][O1];
#pragma unroll
  for (int o = 0; o < O1; ++o) {
    const float bv = b1[o * HW1 + hw];
#pragma unroll
    for (int j = 0; j < BJ1; ++j) acc[j][o] = bv;
  }

  const float* xbase = x + (size_t)bg * IMG1 + (size_t)(ho * 4) * W1 + wo * 4;
  const float* wbase = w1t + (size_t)hw * O1;
  constexpr size_t WS = (size_t)HW1 * O1;

  float xA[BJ1][6], xB[BJ1][6];
  float4 wA[6][2], wB[6][2];

#define LC1_LD(K, XV, WV)                                                      \
  do {                                                                         \
    const int c_ = (K) / 6, kh_ = (K) - c_ * 6;                                \
    const int xo_ = c_ * PLANE1 + kh_ * W1;                                    \
    _Pragma("unroll") for (int j = 0; j < BJ1; ++j) {                          \
      const float* xr = xbase + (size_t)j * IMG1 + xo_;                        \
      const float2 a0 = *reinterpret_cast<const float2*>(xr);                  \
      const float2 a1 = *reinterpret_cast<const float2*>(xr + 2);              \
      const float2 a2 = *reinterpret_cast<const float2*>(xr + 4);              \
      XV[j][0] = a0.x; XV[j][1] = a0.y; XV[j][2] = a1.x;                       \
      XV[j][3] = a1.y; XV[j][4] = a2.x; XV[j][5] = a2.y;                       \
    }                                                                          \
    const float* wp = wbase + (size_t)((K) * 6) * WS;                          \
    _Pragma("unroll") for (int kw = 0; kw < 6; ++kw) {                         \
      WV[kw][0] = *reinterpret_cast<const float4*>(wp + (size_t)kw * WS);      \
      WV[kw][1] = *reinterpret_cast<const float4*>(wp + (size_t)kw * WS + 4);  \
    }                                                                          \
  } while (0)

#define LC1_FMA(XV, WV)                                                        \
  do {                                                                         \
    _Pragma("unroll") for (int kw = 0; kw < 6; ++kw) {                         \
      _Pragma("unroll") for (int j = 0; j < BJ1; ++j) {                        \
        const float xs = XV[j][kw];                                            \
        acc[j][0] = fmaf(xs, WV[kw][0].x, acc[j][0]);                          \
        acc[j][1] = fmaf(xs, WV[kw][0].y, acc[j][1]);                          \
        acc[j][2] = fmaf(xs, WV[kw][0].z, acc[j][2]);                          \
        acc[j][3] = fmaf(xs, WV[kw][0].w, acc[j][3]);                          \
        acc[j][4] = fmaf(xs, WV[kw][1].x, acc[j][4]);                          \
        acc[j][5] = fmaf(xs, WV[kw][1].y, acc[j][5]);                          \
        acc[j][6] = fmaf(xs, WV[kw][1].z, acc[j][6]);                          \
        acc[j][7] = fmaf(xs, WV[kw][1].w, acc[j][7]);                          \
      }                                                                        \
    }                                                                          \
  } while (0)

  LC1_LD(0, xA, wA);
#pragma unroll 1
  for (int k = 0; k < 18; k += 2) {
    LC1_LD(k + 1, xB, wB);                // chunk k+1 in flight
    __builtin_amdgcn_sched_barrier(0);    // pin loads above compute
    LC1_FMA(xA, wA);                      // compute chunk k (landed last iter)
    if (k + 2 < 18) LC1_LD(k + 2, xA, wA);
    __builtin_amdgcn_sched_barrier(0);
    LC1_FMA(xB, wB);                      // compute chunk k+1
  }
#undef LC1_LD
#undef LC1_FMA

#pragma unroll
  for (int j = 0; j < BJ1; ++j) {
    float* op = h1 + ((size_t)(bg + j) * O1) * HW1 + hw;
#pragma unroll
    for (int o = 0; o < O1; ++o) op[(size_t)o * HW1] = fmaxf(acc[j][o], 0.f);
  }
}

// ---- locally-connected layer 2 + ReLU, GEMM-ified per spatial location.
__global__ __launch_bounds__(256) void lc2_kernel(const float* __restrict__ h1,
                                                  const float* __restrict__ w2t,
                                                  const float* __restrict__ b2,
                                                  float* __restrict__ h2) {
  __shared__ float ws[P2 * O2];                 // 18432 B
  const int hw = blockIdx.x;
  const int lane = threadIdx.x & 63;
  const int og = threadIdx.x >> 6;
  const int b = blockIdx.y * 64 + lane;
  const int ho = hw / WO2, wo = hw - ho * WO2;

  for (int i = threadIdx.x; i < P2 * O2; i += 256) {
    const int p = i >> 4, o = i & 15;
    ws[i] = w2t[((size_t)p * HW2 + hw) * O2 + o];
  }
  __syncthreads();

  float acc[4];
#pragma unroll
  for (int oi = 0; oi < 4; ++oi) acc[oi] = b2[(og * 4 + oi) * HW2 + hw];

  const float* xb = h1 + (size_t)b * IMG2 + (size_t)(ho * 4) * W2c + wo * 4;

#pragma unroll 1
  for (int c = 0; c < C2; ++c) {
    float xv[6][6];
#pragma unroll
    for (int kh = 0; kh < 6; ++kh) {
      const float* xr = xb + c * PLANE2 + kh * W2c;
      const float2 a0 = *reinterpret_cast<const float2*>(xr);
      const float2 a1 = *reinterpret_cast<const float2*>(xr + 2);
      const float2 a2 = *reinterpret_cast<const float2*>(xr + 4);
      xv[kh][0] = a0.x; xv[kh][1] = a0.y;
      xv[kh][2] = a1.x; xv[kh][3] = a1.y;
      xv[kh][4] = a2.x; xv[kh][5] = a2.y;
    }
    __builtin_amdgcn_sched_barrier(0);
#pragma unroll
    for (int kh = 0; kh < 6; ++kh) {
#pragma unroll
      for (int kw = 0; kw < 6; ++kw) {
        const int p = (c * 6 + kh) * 6 + kw;
        const float4 wv = *reinterpret_cast<const float4*>(&ws[p * O2 + og * 4]);
        acc[0] = fmaf(xv[kh][kw], wv.x, acc[0]);
        acc[1] = fmaf(xv[kh][kw], wv.y, acc[1]);
        acc[2] = fmaf(xv[kh][kw], wv.z, acc[2]);
        acc[3] = fmaf(xv[kh][kw], wv.w, acc[3]);
      }
    }
  }

#pragma unroll
  for (int oi = 0; oi < 4; ++oi) {
    h2[((size_t)b * O2 + og * 4 + oi) * HW2 + hw] = fmaxf(acc[oi], 0.f);
  }
}

// ---- fused head, batched 8 rows/block: weights read 32x not 256x.
constexpr int HB = 8;
__global__ __launch_bounds__(512) void head_kernel(const float* __restrict__ h2,
                                                   const float* __restrict__ fc1w,
                                                   const float* __restrict__ fc1b,
                                                   const float* __restrict__ fc2w,
                                                   const float* __restrict__ fc2b,
                                                   float* __restrict__ out) {
  __shared__ __align__(16) float sp[HB][NPOOL];   // 15360 B
  __shared__ __align__(16) float sh[HB][304];     //  9728 B (304: float4-friendly)
  __shared__ float sl[HB][N2];                    //  6400 B
  const int bg = blockIdx.x * HB;
  const int tid = threadIdx.x, wv = tid >> 6, ln = tid & 63;

  for (int i = tid; i < HB * NPOOL; i += 512) {
    const int b = i / NPOOL, r = i - b * NPOOL;
    const int o = r / 30, r2 = r - o * 30, ii = r2 / 5, j = r2 - ii * 5;
    const float* base =
        h2 + ((size_t)((bg + b) * O2 + o) * HO2 + 2 * ii) * WO2 + 2 * j;
    sp[b][r] = fmaxf(fmaxf(base[0], base[1]), fmaxf(base[WO2], base[WO2 + 1]));
  }
  __syncthreads();

  // fc1: hold all 8 batch p-fragments in registers; each weight row read once.
  {
    float4 p0[HB], p1[HB];
#pragma unroll
    for (int b = 0; b < HB; ++b) {
      const float4* s4 = reinterpret_cast<const float4*>(sp[b]);
      p0[b] = s4[ln];
      p1[b] = (ln < 56) ? s4[64 + ln] : make_float4(0.f, 0.f, 0.f, 0.f);
    }
    for (int n = wv; n < N1; n += 8) {
      const float4* wr = reinterpret_cast<const float4*>(fc1w + (size_t)n * NPOOL);
      const float4 a0 = wr[ln];
      const float4 a1 = (ln < 56) ? wr[64 + ln] : make_float4(0.f, 0.f, 0.f, 0.f);
#pragma unroll
      for (int b = 0; b < HB; ++b) {
        float s = fmaf(a0.x, p0[b].x, fmaf(a0.y, p0[b].y,
                  fmaf(a0.z, p0[b].z, a0.w * p0[b].w)));
        s = fmaf(a1.x, p1[b].x, fmaf(a1.y, p1[b].y,
            fmaf(a1.z, p1[b].z, fmaf(a1.w, p1[b].w, s))));
#pragma unroll
        for (int off = 32; off > 0; off >>= 1) s += __shfl_xor(s, off, 64);
        if (ln == 0) sh[b][n] = fmaxf(s + fc1b[n], 0.f);
      }
    }
  }
  __syncthreads();

  // fc2 (300 -> 200)
  {
    float4 q0[HB], q1[HB];
#pragma unroll
    for (int b = 0; b < HB; ++b) {
      const float4* s4 = reinterpret_cast<const float4*>(sh[b]);
      q0[b] = s4[ln];
      q1[b] = (ln < 11) ? s4[64 + ln] : make_float4(0.f, 0.f, 0.f, 0.f);
    }
    for (int n = wv; n < N2; n += 8) {
      const float4* wr = reinterpret_cast<const float4*>(fc2w + (size_t)n * N1);
      const float4 a0 = wr[ln];
      const float4 a1 = (ln < 11) ? wr[64 + ln] : make_float4(0.f, 0.f, 0.f, 0.f);
#pragma unroll
      for (int b = 0; b < HB; ++b) {
        float s = fmaf(a0.x, q0[b].x, fmaf(a0.y, q0[b].y,
                  fmaf(a0.z, q0[b].z, a0.w * q0[b].w)));
        s = fmaf(a1.x, q1[b].x, fmaf(a1.y, q1[b].y,
            fmaf(a1.z, q1[b].z, fmaf(a1.w, q1[b].w, s))));
#pragma unroll
        for (int off = 32; off > 0; off >>= 1) s += __shfl_xor(s, off, 64);
        if (ln == 0) sl[b][n] = s + fc2b[n];
      }
    }
  }
  __syncthreads();

  // softmax: wave wv owns batch row wv.
  {
    const float v0 = sl[wv][ln], v1 = sl[wv][64 + ln], v2 = sl[wv][128 + ln];
    const float vt = (ln < 8) ? sl[wv][192 + ln] : -INFINITY;
    float m = fmaxf(fmaxf(v0, v1), fmaxf(v2, vt));
#pragma unroll
    for (int off = 32; off > 0; off >>= 1) m = fmaxf(m, __shfl_xor(m, off, 64));
    const float e0 = expf(v0 - m), e1 = expf(v1 - m), e2 = expf(v2 - m);
    const float et = (ln < 8) ? expf(vt - m) : 0.f;
    float s = e0 + e1 + e2 + et;
#pragma unroll
    for (int off = 32; off > 0; off >>= 1) s += __shfl_xor(s, off, 64);
    const float inv = 1.f / s;
    float* orow = out + (size_t)(bg + wv) * N2;
    orow[ln] = e0 * inv;
    orow[64 + ln] = e1 * inv;
    orow[128 + ln] = e2 * inv;
    if (ln < 8) orow[192 + ln] = et * inv;
  }
}

}  // namespace

extern "C" void kernel_launch(void* const* d_in, const int* in_sizes, int n_in,
                              void* d_out, int out_size, void* d_ws, size_t ws_size,
                              hipStream_t stream) {
  const float* x     = (const float*)d_in[0];
  const float* w1    = (const float*)d_in[1];
  const float* b1    = (const float*)d_in[2];
  const float* w2    = (const float*)d_in[3];
  const float* b2    = (const float*)d_in[4];
  const float* fc1_w = (const float*)d_in[5];
  const float* fc1_b = (const float*)d_in[6];
  const float* fc2_w = (const float*)d_in[7];
  const float* fc2_b = (const float*)d_in[8];
  float* out = (float*)d_out;

  float* ws  = (float*)d_ws;
  float* w1t = ws;                                  // 2,052,864 f
  float* w2t = w1t + (size_t)O1 * P1 * HW1;         //   599,040 f
  float* h1  = w2t + (size_t)O2 * P2 * HW2;         // 4,866,048 f  (B,O,HW)
  float* h2  = h1 + (size_t)BATCH * O1 * HW1;       //   532,480 f

  wt1_kernel<<<(P1 * HW1 + 255) / 256, 256, 0, stream>>>(w1, w1t);
  wt2_kernel<<<(P2 * HW2 + 255) / 256, 256, 0, stream>>>(w2, w2t);
  lc1_kernel<<<dim3((HW1 + 63) / 64, BATCH / NB1), 512, 0, stream>>>(x, w1t, b1, h1);
  lc2_kernel<<<dim3(HW2, 4), 256, 0, stream>>>(h1, w2t, b2, h2);
  head_kernel<<<BATCH / HB, 512, 0, stream>>>(h2, fc1_w, fc1_b, fc2_w, fc2_b, out);
}

// Round 11
// 187.639 us; speedup vs baseline: 1.5101x; 1.5101x over previous
//
#include <hip/hip_runtime.h>
#include <cmath>

namespace {

constexpr int BATCH = 256;
// layer 1
constexpr int C1 = 3, H1 = 218, W1 = 178;
constexpr int IMG1 = C1 * H1 * W1;            // 116412
constexpr int PLANE1 = H1 * W1;               // 38804
constexpr int O1 = 8, HO1 = 54, WO1 = 44;
constexpr int HW1 = HO1 * WO1;                // 2376
constexpr int P1 = C1 * 36;                   // 108
// layer 2
constexpr int C2 = 8, H2c = 54, W2c = 44;
constexpr int IMG2 = C2 * H2c * W2c;          // 19008
constexpr int PLANE2 = H2c * W2c;             // 2376
constexpr int O2 = 16, HO2 = 13, WO2 = 10;
constexpr int HW2 = HO2 * WO2;                // 130
constexpr int P2 = C2 * 36;                   // 288
// head
constexpr int NPOOL = 480;                    // 16*6*5
constexpr int N1 = 300, N2 = 200;

// lc1: 512 thr = 8 waves x 64 hw-lanes; wave = 4 batches -> NB=32/block.
constexpr int BJ1 = 4;
constexpr int NB1 = 32;
constexpr int WLDS_CH = 6 * 4 * 128;          // words per w chunk buffer

// ---- transpose w1 (O1,P1,HW1) -> (P1*HW1, O1)
__global__ __launch_bounds__(256) void wt1_kernel(const float* __restrict__ w,
                                                  float* __restrict__ wt) {
  const int idx = blockIdx.x * 256 + threadIdx.x;   // p*HW1 + hw
  if (idx >= P1 * HW1) return;
  float v[O1];
#pragma unroll
  for (int o = 0; o < O1; ++o) v[o] = w[(size_t)o * (P1 * HW1) + idx];
  float4* dst = reinterpret_cast<float4*>(wt + (size_t)idx * O1);
  dst[0] = make_float4(v[0], v[1], v[2], v[3]);
  dst[1] = make_float4(v[4], v[5], v[6], v[7]);
}

// ---- transpose w2 (O2,P2,HW2) -> (P2*HW2, O2)
__global__ __launch_bounds__(256) void wt2_kernel(const float* __restrict__ w,
                                                  float* __restrict__ wt) {
  const int idx = blockIdx.x * 256 + threadIdx.x;   // p*HW2 + hw
  if (idx >= P2 * HW2) return;
  float v[O2];
#pragma unroll
  for (int o = 0; o < O2; ++o) v[o] = w[(size_t)o * (P2 * HW2) + idx];
  float4* dst = reinterpret_cast<float4*>(wt + (size_t)idx * O2);
  dst[0] = make_float4(v[0], v[1], v[2], v[3]);
  dst[1] = make_float4(v[4], v[5], v[6], v[7]);
  dst[2] = make_float4(v[8], v[9], v[10], v[11]);
  dst[3] = make_float4(v[12], v[13], v[14], v[15]);
}

// ---- locally-connected layer 1 + ReLU.
// w stream staged through LDS once per BLOCK (8 waves share it) instead of
// once per wave: w L1-line touches drop 8x (r2-r10 ledger: lc1 time tracks
// per-CU line-transactions, invariant ~100us across all scheduling fixes).
// x stays direct-to-register with 1-chunk prefetch (r10 pattern).
// Single barrier per chunk; ds_write's source regs were loaded one full
// chunk earlier (no vmcnt stall at the write - r8's failure mode).
__global__ __launch_bounds__(512) void lc1_kernel(const float* __restrict__ x,
                                                  const float* __restrict__ w1t,
                                                  const float* __restrict__ b1,
                                                  float* __restrict__ h1) {
  __shared__ __align__(16) float wlds[2 * WLDS_CH];   // 24576 B
  const int t = threadIdx.x;
  const int lane = t & 63;
  const int wave = t >> 6;
  const int hw0 = blockIdx.x * 64;
  const int hw = hw0 + lane;
  const bool valid = hw < HW1;
  const int hwc = valid ? hw : HW1 - 1;     // clamped: loads in-bounds, store masked
  const int bg = blockIdx.y * NB1 + wave * BJ1;
  const int ho = hwc / WO1, wo = hwc - ho * WO1;

  float acc[BJ1][O1];
#pragma unroll
  for (int o = 0; o < O1; ++o) {
    const float bv = b1[o * HW1 + hwc];
#pragma unroll
    for (int j = 0; j < BJ1; ++j) acc[j][o] = bv;
  }

  const float* xbase = x + (size_t)bg * IMG1 + (size_t)(ho * 4) * W1 + wo * 4;

  // staging decomposition: 768 float4 per chunk = [kw(6)][shw(64)][o4(2)]
  int g_off[2], l_off[2];
#pragma unroll
  for (int s = 0; s < 2; ++s) {
    int idx = s ? (t + 512 < 768 ? t + 512 : 767) : t;   // dup tail: same-value LDS race, benign
    const int kw = idx >> 7, r = idx & 127, shw = r >> 1, o4 = (r & 1) * 4;
    const int ghw = hw0 + shw < HW1 ? hw0 + shw : HW1 - 1;
    g_off[s] = kw * (HW1 * 8) + ghw * 8 + o4;
    l_off[s] = (kw * 4 + (o4 >> 1)) * 128 + shw * 2;     // word offset (first b64)
  }

  float xA[BJ1][6], xB[BJ1][6];
  float4 wr[2];

#define LC1_WLOAD(K)                                                           \
  do {                                                                         \
    const float* wp = w1t + (size_t)(K) * (6 * HW1 * 8);                       \
    wr[0] = *reinterpret_cast<const float4*>(wp + g_off[0]);                   \
    wr[1] = *reinterpret_cast<const float4*>(wp + g_off[1]);                   \
  } while (0)

#define LC1_WWRITE(BUF)                                                        \
  do {                                                                         \
    float* wb_ = wlds + (BUF) * WLDS_CH;                                       \
    _Pragma("unroll") for (int s = 0; s < 2; ++s) {                            \
      *reinterpret_cast<float2*>(&wb_[l_off[s]]) = make_float2(wr[s].x, wr[s].y); \
      *reinterpret_cast<float2*>(&wb_[l_off[s] + 128]) = make_float2(wr[s].z, wr[s].w); \
    }                                                                          \
  } while (0)

#define LC1_XLOAD(K, XV)                                                       \
  do {                                                                         \
    const int c_ = (K) / 6, kh_ = (K) - c_ * 6;                                \
    const int xo_ = c_ * PLANE1 + kh_ * W1;                                    \
    _Pragma("unroll") for (int j = 0; j < BJ1; ++j) {                          \
      const float* xr = xbase + (size_t)j * IMG1 + xo_;                        \
      const float2 a0 = *reinterpret_cast<const float2*>(xr);                  \
      const float2 a1 = *reinterpret_cast<const float2*>(xr + 2);              \
      const float2 a2 = *reinterpret_cast<const float2*>(xr + 4);              \
      XV[j][0] = a0.x; XV[j][1] = a0.y; XV[j][2] = a1.x;                       \
      XV[j][3] = a1.y; XV[j][4] = a2.x; XV[j][5] = a2.y;                       \
    }                                                                          \
  } while (0)

#define LC1_COMPUTE(BUF, XV)                                                   \
  do {                                                                         \
    const float2* wb_ = reinterpret_cast<const float2*>(wlds + (BUF) * WLDS_CH); \
    _Pragma("unroll") for (int kw = 0; kw < 6; ++kw) {                         \
      const float2 w01 = wb_[(kw * 4 + 0) * 64 + lane];                        \
      const float2 w23 = wb_[(kw * 4 + 1) * 64 + lane];                        \
      const float2 w45 = wb_[(kw * 4 + 2) * 64 + lane];                        \
      const float2 w67 = wb_[(kw * 4 + 3) * 64 + lane];                        \
      _Pragma("unroll") for (int j = 0; j < BJ1; ++j) {                        \
        const float xs = XV[j][kw];                                            \
        acc[j][0] = fmaf(xs, w01.x, acc[j][0]);                                \
        acc[j][1] = fmaf(xs, w01.y, acc[j][1]);                                \
        acc[j][2] = fmaf(xs, w23.x, acc[j][2]);                                \
        acc[j][3] = fmaf(xs, w23.y, acc[j][3]);                                \
        acc[j][4] = fmaf(xs, w45.x, acc[j][4]);                                \
        acc[j][5] = fmaf(xs, w45.y, acc[j][5]);                                \
        acc[j][6] = fmaf(xs, w67.x, acc[j][6]);                                \
        acc[j][7] = fmaf(xs, w67.y, acc[j][7]);                                \
      }                                                                        \
    }                                                                          \
  } while (0)

  // prologue
  LC1_WLOAD(0);
  LC1_XLOAD(0, xA);
  LC1_WWRITE(0);                 // one-time vmcnt stall (~900 cy), once per block
  LC1_WLOAD(1);
  LC1_XLOAD(1, xB);
  __syncthreads();               // buf0 ready

#pragma unroll 1
  for (int k = 0; k < 18; ++k) {
    if (k & 1) LC1_COMPUTE(1, xB);
    else       LC1_COMPUTE(0, xA);
    if (k < 17) LC1_WWRITE((k + 1) & 1);   // wr = w(k+1), loaded last iter: landed
    if (k < 16) {
      LC1_WLOAD(k + 2);
      if (k & 1) LC1_XLOAD(k + 2, xB);
      else       LC1_XLOAD(k + 2, xA);
    }
    __syncthreads();
  }
#undef LC1_WLOAD
#undef LC1_WWRITE
#undef LC1_XLOAD
#undef LC1_COMPUTE

  if (valid) {
#pragma unroll
    for (int j = 0; j < BJ1; ++j) {
      float* op = h1 + ((size_t)(bg + j) * O1) * HW1 + hw;
#pragma unroll
      for (int o = 0; o < O1; ++o) op[(size_t)o * HW1] = fmaxf(acc[j][o], 0.f);
    }
  }
}

// ---- locally-connected layer 2 + ReLU, GEMM-ified per spatial location.
__global__ __launch_bounds__(256) void lc2_kernel(const float* __restrict__ h1,
                                                  const float* __restrict__ w2t,
                                                  const float* __restrict__ b2,
                                                  float* __restrict__ h2) {
  __shared__ float ws[P2 * O2];                 // 18432 B
  const int hw = blockIdx.x;
  const int lane = threadIdx.x & 63;
  const int og = threadIdx.x >> 6;
  const int b = blockIdx.y * 64 + lane;
  const int ho = hw / WO2, wo = hw - ho * WO2;

  for (int i = threadIdx.x; i < P2 * O2; i += 256) {
    const int p = i >> 4, o = i & 15;
    ws[i] = w2t[((size_t)p * HW2 + hw) * O2 + o];
  }
  __syncthreads();

  float acc[4];
#pragma unroll
  for (int oi = 0; oi < 4; ++oi) acc[oi] = b2[(og * 4 + oi) * HW2 + hw];

  const float* xb = h1 + (size_t)b * IMG2 + (size_t)(ho * 4) * W2c + wo * 4;

#pragma unroll 1
  for (int c = 0; c < C2; ++c) {
    float xv[6][6];
#pragma unroll
    for (int kh = 0; kh < 6; ++kh) {
      const float* xr = xb + c * PLANE2 + kh * W2c;
      const float2 a0 = *reinterpret_cast<const float2*>(xr);
      const float2 a1 = *reinterpret_cast<const float2*>(xr + 2);
      const float2 a2 = *reinterpret_cast<const float2*>(xr + 4);
      xv[kh][0] = a0.x; xv[kh][1] = a0.y;
      xv[kh][2] = a1.x; xv[kh][3] = a1.y;
      xv[kh][4] = a2.x; xv[kh][5] = a2.y;
    }
    __builtin_amdgcn_sched_barrier(0);
#pragma unroll
    for (int kh = 0; kh < 6; ++kh) {
#pragma unroll
      for (int kw = 0; kw < 6; ++kw) {
        const int p = (c * 6 + kh) * 6 + kw;
        const float4 wv = *reinterpret_cast<const float4*>(&ws[p * O2 + og * 4]);
        acc[0] = fmaf(xv[kh][kw], wv.x, acc[0]);
        acc[1] = fmaf(xv[kh][kw], wv.y, acc[1]);
        acc[2] = fmaf(xv[kh][kw], wv.z, acc[2]);
        acc[3] = fmaf(xv[kh][kw], wv.w, acc[3]);
      }
    }
  }

#pragma unroll
  for (int oi = 0; oi < 4; ++oi) {
    h2[((size_t)b * O2 + og * 4 + oi) * HW2 + hw] = fmaxf(acc[oi], 0.f);
  }
}

// ---- fused head: maxpool(2) -> FC1+ReLU -> FC2 -> softmax.
// one block (512 thr = 8 waves) per batch row (round-9 proven version;
// round-10's 8-row batching spilled its per-batch fragments to scratch).
__global__ __launch_bounds__(512) void head_kernel(const float* __restrict__ h2,
                                                   const float* __restrict__ fc1w,
                                                   const float* __restrict__ fc1b,
                                                   const float* __restrict__ fc2w,
                                                   const float* __restrict__ fc2b,
                                                   float* __restrict__ out) {
  __shared__ __align__(16) float sp[NPOOL];
  __shared__ __align__(16) float sh[N1];
  __shared__ float sl[N2];
  __shared__ float red[2];
  const int b = blockIdx.x;
  const int tid = threadIdx.x;

  if (tid < NPOOL) {
    const int o = tid / 30, r2 = tid - o * 30;
    const int i = r2 / 5, j = r2 - i * 5;
    const float* base = h2 + ((size_t)(b * O2 + o) * HO2 + 2 * i) * WO2 + 2 * j;
    sp[tid] = fmaxf(fmaxf(base[0], base[1]), fmaxf(base[WO2], base[WO2 + 1]));
  }
  __syncthreads();

  const int wv = tid >> 6, ln = tid & 63;
  const float4* sp4 = reinterpret_cast<const float4*>(sp);
  for (int n = wv; n < N1; n += 8) {
    const float4* wr = reinterpret_cast<const float4*>(fc1w + (size_t)n * NPOOL);
    float4 a = wr[ln], p = sp4[ln];
    float s = fmaf(a.x, p.x, fmaf(a.y, p.y, fmaf(a.z, p.z, a.w * p.w)));
    if (ln < 56) {
      float4 a2 = wr[64 + ln], p2 = sp4[64 + ln];
      s = fmaf(a2.x, p2.x, fmaf(a2.y, p2.y, fmaf(a2.z, p2.z, fmaf(a2.w, p2.w, s))));
    }
#pragma unroll
    for (int off = 32; off > 0; off >>= 1) s += __shfl_xor(s, off, 64);
    if (ln == 0) sh[n] = fmaxf(s + fc1b[n], 0.f);
  }
  __syncthreads();

  const float4* sh4 = reinterpret_cast<const float4*>(sh);
  for (int n = wv; n < N2; n += 8) {
    const float4* wr = reinterpret_cast<const float4*>(fc2w + (size_t)n * N1);
    float4 a = wr[ln], p = sh4[ln];
    float s = fmaf(a.x, p.x, fmaf(a.y, p.y, fmaf(a.z, p.z, a.w * p.w)));
    if (ln < 11) {
      float4 a2 = wr[64 + ln], p2 = sh4[64 + ln];
      s = fmaf(a2.x, p2.x, fmaf(a2.y, p2.y, fmaf(a2.z, p2.z, fmaf(a2.w, p2.w, s))));
    }
#pragma unroll
    for (int off = 32; off > 0; off >>= 1) s += __shfl_xor(s, off, 64);
    if (ln == 0) sl[n] = s + fc2b[n];
  }
  __syncthreads();

  if (wv == 0) {
    float m = fmaxf(fmaxf(sl[ln], sl[ln + 64]), sl[ln + 128]);
    if (ln < 8) m = fmaxf(m, sl[192 + ln]);
#pragma unroll
    for (int off = 32; off > 0; off >>= 1) m = fmaxf(m, __shfl_xor(m, off, 64));
    if (ln == 0) red[0] = m;
  }
  __syncthreads();
  const float mx = red[0];
  if (tid < N2) sl[tid] = expf(sl[tid] - mx);
  __syncthreads();
  if (wv == 0) {
    float s = sl[ln] + sl[ln + 64] + sl[ln + 128] + (ln < 8 ? sl[192 + ln] : 0.f);
#pragma unroll
    for (int off = 32; off > 0; off >>= 1) s += __shfl_xor(s, off, 64);
    if (ln == 0) red[1] = s;
  }
  __syncthreads();
  if (tid < N2) out[(size_t)b * N2 + tid] = sl[tid] / red[1];
}

}  // namespace

extern "C" void kernel_launch(void* const* d_in, const int* in_sizes, int n_in,
                              void* d_out, int out_size, void* d_ws, size_t ws_size,
                              hipStream_t stream) {
  const float* x     = (const float*)d_in[0];
  const float* w1    = (const float*)d_in[1];
  const float* b1    = (const float*)d_in[2];
  const float* w2    = (const float*)d_in[3];
  const float* b2    = (const float*)d_in[4];
  const float* fc1_w = (const float*)d_in[5];
  const float* fc1_b = (const float*)d_in[6];
  const float* fc2_w = (const float*)d_in[7];
  const float* fc2_b = (const float*)d_in[8];
  float* out = (float*)d_out;

  float* ws  = (float*)d_ws;
  float* w1t = ws;                                  // 2,052,864 f
  float* w2t = w1t + (size_t)O1 * P1 * HW1;         //   599,040 f
  float* h1  = w2t + (size_t)O2 * P2 * HW2;         // 4,866,048 f  (B,O,HW)
  float* h2  = h1 + (size_t)BATCH * O1 * HW1;       //   532,480 f

  wt1_kernel<<<(P1 * HW1 + 255) / 256, 256, 0, stream>>>(w1, w1t);
  wt2_kernel<<<(P2 * HW2 + 255) / 256, 256, 0, stream>>>(w2, w2t);
  lc1_kernel<<<dim3((HW1 + 63) / 64, BATCH / NB1), 512, 0, stream>>>(x, w1t, b1, h1);
  lc2_kernel<<<dim3(HW2, 4), 256, 0, stream>>>(h1, w2t, b2, h2);
  head_kernel<<<BATCH, 512, 0, stream>>>(h2, fc1_w, fc1_b, fc2_w, fc2_b, out);
}

// Round 12
// 173.170 us; speedup vs baseline: 1.6363x; 1.0836x over previous
//
#include <hip/hip_runtime.h>
#include <cmath>

namespace {

constexpr int BATCH = 256;
// layer 1
constexpr int C1 = 3, H1 = 218, W1 = 178;
constexpr int IMG1 = C1 * H1 * W1;            // 116412
constexpr int PLANE1 = H1 * W1;               // 38804
constexpr int O1 = 8, HO1 = 54, WO1 = 44;
constexpr int HW1 = HO1 * WO1;                // 2376
constexpr int P1 = C1 * 36;                   // 108
// layer 2
constexpr int C2 = 8, H2c = 54, W2c = 44;
constexpr int IMG2 = C2 * H2c * W2c;          // 19008
constexpr int PLANE2 = H2c * W2c;             // 2376
constexpr int O2 = 16, HO2 = 13, WO2 = 10;
constexpr int HW2 = HO2 * WO2;                // 130
constexpr int P2 = C2 * 36;                   // 288
// head
constexpr int NPOOL = 480;                    // 16*6*5
constexpr int N1 = 300, N2 = 200;

// lc1 v3: block = 16 hw x 64 batches, 256 thr (4 waves).
// Full w-slice LDS-resident (one barrier/block; r11 evidence: per-chunk
// __syncthreads drains vmcnt(0) -> 18 HBM-latency stalls/block was the bind).
constexpr int THW = 16;
constexpr int NBB = 64;
constexpr int BJ = 4;

// ---- transpose w2 (O2,P2,HW2) -> (P2*HW2, O2)
__global__ __launch_bounds__(256) void wt2_kernel(const float* __restrict__ w,
                                                  float* __restrict__ wt) {
  const int idx = blockIdx.x * 256 + threadIdx.x;   // p*HW2 + hw
  if (idx >= P2 * HW2) return;
  float v[O2];
#pragma unroll
  for (int o = 0; o < O2; ++o) v[o] = w[(size_t)o * (P2 * HW2) + idx];
  float4* dst = reinterpret_cast<float4*>(wt + (size_t)idx * O2);
  dst[0] = make_float4(v[0], v[1], v[2], v[3]);
  dst[1] = make_float4(v[4], v[5], v[6], v[7]);
  dst[2] = make_float4(v[8], v[9], v[10], v[11]);
  dst[3] = make_float4(v[12], v[13], v[14], v[15]);
}

// ---- locally-connected layer 1 + ReLU.
// LDS layout: wl[p][o2(4)][hw(16)][2] words -> ds_read_b64 is conflict-free
// (16 hwl-lanes cover all 32 banks once; 4 b2-lanes broadcast). Reads w1
// (O,P,HW) directly - no transpose kernel needed.
__global__ __launch_bounds__(256, 2) void lc1_kernel(const float* __restrict__ x,
                                                     const float* __restrict__ w1,
                                                     const float* __restrict__ b1,
                                                     float* __restrict__ h1) {
  __shared__ float wl[P1 * 128];                // 55296 B
  const int t = threadIdx.x;
  const int wave = t >> 6, lane = t & 63;
  const int b2 = lane >> 4, hwl = lane & 15;
  const int hw0 = blockIdx.x * THW;
  const int hw = hw0 + hwl;
  const bool valid = hw < HW1;
  const int hwc = valid ? hw : HW1 - 1;
  const int ho = hwc / WO1, wo = hwc - ho * WO1;
  const int bb = blockIdx.y * NBB + wave * 16 + b2 * BJ;

  // ---- stage the block's full w slice: 108p x 16hw x 8o = 3456 float4 reads
  for (int i = t; i < 3456; i += 256) {
    const int o = i / 432, r = i - o * 432;
    const int p = r >> 2, q = r & 3;
    int hq = hw0 + q * 4;
    if (hq > HW1 - 4) hq = HW1 - 4;             // tail clamp (dup write, benign)
    const float4 wv =
        *reinterpret_cast<const float4*>(w1 + ((size_t)o * P1 + p) * HW1 + hq);
    const int base = p * 128 + (o >> 1) * 32 + (hq - hw0) * 2 + (o & 1);
    wl[base] = wv.x;
    wl[base + 2] = wv.y;
    wl[base + 4] = wv.z;
    wl[base + 6] = wv.w;
  }

  float acc[BJ][O1];
#pragma unroll
  for (int o = 0; o < O1; ++o) {
    const float bv = b1[o * HW1 + hwc];
#pragma unroll
    for (int j = 0; j < BJ; ++j) acc[j][o] = bv;
  }

  const float* xbase = x + (size_t)bb * IMG1 + (size_t)(ho * 4) * W1 + wo * 4;

  __syncthreads();                              // the ONLY barrier

  float xA[BJ][6], xB[BJ][6];

#define LC1_LD(K, XV)                                                          \
  do {                                                                         \
    const int c_ = (K) / 6, kh_ = (K) - c_ * 6;                                \
    const int xo_ = c_ * PLANE1 + kh_ * W1;                                    \
    _Pragma("unroll") for (int j = 0; j < BJ; ++j) {                           \
      const float* xr = xbase + (size_t)j * IMG1 + xo_;                        \
      const float2 a0 = *reinterpret_cast<const float2*>(xr);                  \
      const float2 a1 = *reinterpret_cast<const float2*>(xr + 2);              \
      const float2 a2 = *reinterpret_cast<const float2*>(xr + 4);              \
      XV[j][0] = a0.x; XV[j][1] = a0.y; XV[j][2] = a1.x;                       \
      XV[j][3] = a1.y; XV[j][4] = a2.x; XV[j][5] = a2.y;                       \
    }                                                                          \
  } while (0)

#define LC1_FMA(K, XV)                                                         \
  do {                                                                         \
    const float2* wb_ = reinterpret_cast<const float2*>(wl);                   \
    _Pragma("unroll") for (int kw = 0; kw < 6; ++kw) {                         \
      const int p_ = (K) * 6 + kw;                                             \
      const float2 w01 = wb_[p_ * 64 + hwl];                                   \
      const float2 w23 = wb_[p_ * 64 + 16 + hwl];                              \
      const float2 w45 = wb_[p_ * 64 + 32 + hwl];                              \
      const float2 w67 = wb_[p_ * 64 + 48 + hwl];                              \
      _Pragma("unroll") for (int j = 0; j < BJ; ++j) {                         \
        const float xs = XV[j][kw];                                            \
        acc[j][0] = fmaf(xs, w01.x, acc[j][0]);                                \
        acc[j][1] = fmaf(xs, w01.y, acc[j][1]);                                \
        acc[j][2] = fmaf(xs, w23.x, acc[j][2]);                                \
        acc[j][3] = fmaf(xs, w23.y, acc[j][3]);                                \
        acc[j][4] = fmaf(xs, w45.x, acc[j][4]);                                \
        acc[j][5] = fmaf(xs, w45.y, acc[j][5]);                                \
        acc[j][6] = fmaf(xs, w67.x, acc[j][6]);                                \
        acc[j][7] = fmaf(xs, w67.y, acc[j][7]);                                \
      }                                                                        \
    }                                                                          \
  } while (0)

  LC1_LD(0, xA);
#pragma unroll 1
  for (int k = 0; k < 18; k += 2) {
    LC1_LD(k + 1, xB);
    __builtin_amdgcn_sched_barrier(0);
    LC1_FMA(k, xA);
    if (k + 2 < 18) LC1_LD(k + 2, xA);
    __builtin_amdgcn_sched_barrier(0);
    LC1_FMA(k + 1, xB);
  }
#undef LC1_LD
#undef LC1_FMA

  if (valid) {
#pragma unroll
    for (int j = 0; j < BJ; ++j) {
      float* op = h1 + ((size_t)(bb + j) * O1) * HW1 + hw;
#pragma unroll
      for (int o = 0; o < O1; ++o) op[(size_t)o * HW1] = fmaxf(acc[j][o], 0.f);
    }
  }
}

// ---- locally-connected layer 2 + ReLU, GEMM-ified per spatial location.
__global__ __launch_bounds__(256) void lc2_kernel(const float* __restrict__ h1,
                                                  const float* __restrict__ w2t,
                                                  const float* __restrict__ b2,
                                                  float* __restrict__ h2) {
  __shared__ float ws[P2 * O2];                 // 18432 B
  const int hw = blockIdx.x;
  const int lane = threadIdx.x & 63;
  const int og = threadIdx.x >> 6;
  const int b = blockIdx.y * 64 + lane;
  const int ho = hw / WO2, wo = hw - ho * WO2;

  for (int i = threadIdx.x; i < P2 * O2; i += 256) {
    const int p = i >> 4, o = i & 15;
    ws[i] = w2t[((size_t)p * HW2 + hw) * O2 + o];
  }
  __syncthreads();

  float acc[4];
#pragma unroll
  for (int oi = 0; oi < 4; ++oi) acc[oi] = b2[(og * 4 + oi) * HW2 + hw];

  const float* xb = h1 + (size_t)b * IMG2 + (size_t)(ho * 4) * W2c + wo * 4;

#pragma unroll 1
  for (int c = 0; c < C2; ++c) {
    float xv[6][6];
#pragma unroll
    for (int kh = 0; kh < 6; ++kh) {
      const float* xr = xb + c * PLANE2 + kh * W2c;
      const float2 a0 = *reinterpret_cast<const float2*>(xr);
      const float2 a1 = *reinterpret_cast<const float2*>(xr + 2);
      const float2 a2 = *reinterpret_cast<const float2*>(xr + 4);
      xv[kh][0] = a0.x; xv[kh][1] = a0.y;
      xv[kh][2] = a1.x; xv[kh][3] = a1.y;
      xv[kh][4] = a2.x; xv[kh][5] = a2.y;
    }
    __builtin_amdgcn_sched_barrier(0);
#pragma unroll
    for (int kh = 0; kh < 6; ++kh) {
#pragma unroll
      for (int kw = 0; kw < 6; ++kw) {
        const int p = (c * 6 + kh) * 6 + kw;
        const float4 wv = *reinterpret_cast<const float4*>(&ws[p * O2 + og * 4]);
        acc[0] = fmaf(xv[kh][kw], wv.x, acc[0]);
        acc[1] = fmaf(xv[kh][kw], wv.y, acc[1]);
        acc[2] = fmaf(xv[kh][kw], wv.z, acc[2]);
        acc[3] = fmaf(xv[kh][kw], wv.w, acc[3]);
      }
    }
  }

#pragma unroll
  for (int oi = 0; oi < 4; ++oi) {
    h2[((size_t)b * O2 + og * 4 + oi) * HW2 + hw] = fmaxf(acc[oi], 0.f);
  }
}

// ---- fused head: maxpool(2) -> FC1+ReLU -> FC2 -> softmax.
// one block (512 thr = 8 waves) per batch row; all intermediates in LDS.
__global__ __launch_bounds__(512) void head_kernel(const float* __restrict__ h2,
                                                   const float* __restrict__ fc1w,
                                                   const float* __restrict__ fc1b,
                                                   const float* __restrict__ fc2w,
                                                   const float* __restrict__ fc2b,
                                                   float* __restrict__ out) {
  __shared__ __align__(16) float sp[NPOOL];
  __shared__ __align__(16) float sh[N1];
  __shared__ float sl[N2];
  __shared__ float red[2];
  const int b = blockIdx.x;
  const int tid = threadIdx.x;

  if (tid < NPOOL) {
    const int o = tid / 30, r2 = tid - o * 30;
    const int i = r2 / 5, j = r2 - i * 5;
    const float* base = h2 + ((size_t)(b * O2 + o) * HO2 + 2 * i) * WO2 + 2 * j;
    sp[tid] = fmaxf(fmaxf(base[0], base[1]), fmaxf(base[WO2], base[WO2 + 1]));
  }
  __syncthreads();

  const int wv = tid >> 6, ln = tid & 63;
  const float4* sp4 = reinterpret_cast<const float4*>(sp);
  for (int n = wv; n < N1; n += 8) {
    const float4* wr = reinterpret_cast<const float4*>(fc1w + (size_t)n * NPOOL);
    float4 a = wr[ln], p = sp4[ln];
    float s = fmaf(a.x, p.x, fmaf(a.y, p.y, fmaf(a.z, p.z, a.w * p.w)));
    if (ln < 56) {
      float4 a2 = wr[64 + ln], p2 = sp4[64 + ln];
      s = fmaf(a2.x, p2.x, fmaf(a2.y, p2.y, fmaf(a2.z, p2.z, fmaf(a2.w, p2.w, s))));
    }
#pragma unroll
    for (int off = 32; off > 0; off >>= 1) s += __shfl_xor(s, off, 64);
    if (ln == 0) sh[n] = fmaxf(s + fc1b[n], 0.f);
  }
  __syncthreads();

  const float4* sh4 = reinterpret_cast<const float4*>(sh);
  for (int n = wv; n < N2; n += 8) {
    const float4* wr = reinterpret_cast<const float4*>(fc2w + (size_t)n * N1);
    float4 a = wr[ln], p = sh4[ln];
    float s = fmaf(a.x, p.x, fmaf(a.y, p.y, fmaf(a.z, p.z, a.w * p.w)));
    if (ln < 11) {
      float4 a2 = wr[64 + ln], p2 = sh4[64 + ln];
      s = fmaf(a2.x, p2.x, fmaf(a2.y, p2.y, fmaf(a2.z, p2.z, fmaf(a2.w, p2.w, s))));
    }
#pragma unroll
    for (int off = 32; off > 0; off >>= 1) s += __shfl_xor(s, off, 64);
    if (ln == 0) sl[n] = s + fc2b[n];
  }
  __syncthreads();

  if (wv == 0) {
    float m = fmaxf(fmaxf(sl[ln], sl[ln + 64]), sl[ln + 128]);
    if (ln < 8) m = fmaxf(m, sl[192 + ln]);
#pragma unroll
    for (int off = 32; off > 0; off >>= 1) m = fmaxf(m, __shfl_xor(m, off, 64));
    if (ln == 0) red[0] = m;
  }
  __syncthreads();
  const float mx = red[0];
  if (tid < N2) sl[tid] = expf(sl[tid] - mx);
  __syncthreads();
  if (wv == 0) {
    float s = sl[ln] + sl[ln + 64] + sl[ln + 128] + (ln < 8 ? sl[192 + ln] : 0.f);
#pragma unroll
    for (int off = 32; off > 0; off >>= 1) s += __shfl_xor(s, off, 64);
    if (ln == 0) red[1] = s;
  }
  __syncthreads();
  if (tid < N2) out[(size_t)b * N2 + tid] = sl[tid] / red[1];
}

}  // namespace

extern "C" void kernel_launch(void* const* d_in, const int* in_sizes, int n_in,
                              void* d_out, int out_size, void* d_ws, size_t ws_size,
                              hipStream_t stream) {
  const float* x     = (const float*)d_in[0];
  const float* w1    = (const float*)d_in[1];
  const float* b1    = (const float*)d_in[2];
  const float* w2    = (const float*)d_in[3];
  const float* b2    = (const float*)d_in[4];
  const float* fc1_w = (const float*)d_in[5];
  const float* fc1_b = (const float*)d_in[6];
  const float* fc2_w = (const float*)d_in[7];
  const float* fc2_b = (const float*)d_in[8];
  float* out = (float*)d_out;

  float* ws  = (float*)d_ws;
  float* w2t = ws;                                  //   599,040 f
  float* h1  = w2t + (size_t)O2 * P2 * HW2;         // 4,866,048 f  (B,O,HW)
  float* h2  = h1 + (size_t)BATCH * O1 * HW1;       //   532,480 f

  wt2_kernel<<<(P2 * HW2 + 255) / 256, 256, 0, stream>>>(w2, w2t);
  lc1_kernel<<<dim3((HW1 + THW - 1) / THW, BATCH / NBB), 256, 0, stream>>>(x, w1, b1, h1);
  lc2_kernel<<<dim3(HW2, 4), 256, 0, stream>>>(h1, w2t, b2, h2);
  head_kernel<<<BATCH, 512, 0, stream>>>(h2, fc1_w, fc1_b, fc2_w, fc2_b, out);
}

// Round 13
// 138.868 us; speedup vs baseline: 2.0405x; 1.2470x over previous
//
#include <hip/hip_runtime.h>
#include <cmath>

namespace {

constexpr int BATCH = 256;
// layer 1
constexpr int C1 = 3, H1 = 218, W1 = 178;
constexpr int IMG1 = C1 * H1 * W1;            // 116412
constexpr int PLANE1 = H1 * W1;               // 38804
constexpr int O1 = 8, HO1 = 54, WO1 = 44;
constexpr int HW1 = HO1 * WO1;                // 2376
constexpr int P1 = C1 * 36;                   // 108
// layer 2
constexpr int C2 = 8, H2c = 54, W2c = 44;
constexpr int O2 = 16, HO2 = 13, WO2 = 10;
constexpr int HW2 = HO2 * WO2;                // 130
constexpr int P2 = C2 * 36;                   // 288
// head
constexpr int NPOOL = 480;                    // 16*6*5
constexpr int N1 = 300, N2 = 200;

// lc1: block = 16 hw x 64 batches, 256 thr (4 waves); w slice LDS-resident.
constexpr int THW = 16;
constexpr int NBB = 64;
constexpr int BJ = 4;

// ---- transpose w2 (O2,P2,HW2) -> (P2*HW2, O2)
__global__ __launch_bounds__(256) void wt2_kernel(const float* __restrict__ w,
                                                  float* __restrict__ wt) {
  const int idx = blockIdx.x * 256 + threadIdx.x;   // p*HW2 + hw
  if (idx >= P2 * HW2) return;
  float v[O2];
#pragma unroll
  for (int o = 0; o < O2; ++o) v[o] = w[(size_t)o * (P2 * HW2) + idx];
  float4* dst = reinterpret_cast<float4*>(wt + (size_t)idx * O2);
  dst[0] = make_float4(v[0], v[1], v[2], v[3]);
  dst[1] = make_float4(v[4], v[5], v[6], v[7]);
  dst[2] = make_float4(v[8], v[9], v[10], v[11]);
  dst[3] = make_float4(v[12], v[13], v[14], v[15]);
}

// ---- locally-connected layer 1 + ReLU. (r12 structure, unchanged except
// the output store.) Output layout h1t = (O1, HW1, B): each thread owns 4
// consecutive batches -> one aligned float4 store per o; the block's lanes
// fully cover each 64B line. This makes lc2's reads coalescible (r9 vs r12
// ledger: batch-contiguous h1 was worth ~40us in the post-lc1 tail).
__global__ __launch_bounds__(256, 2) void lc1_kernel(const float* __restrict__ x,
                                                     const float* __restrict__ w1,
                                                     const float* __restrict__ b1,
                                                     float* __restrict__ h1t) {
  __shared__ float wl[P1 * 128];                // 55296 B
  const int t = threadIdx.x;
  const int wave = t >> 6, lane = t & 63;
  const int b2 = lane >> 4, hwl = lane & 15;
  const int hw0 = blockIdx.x * THW;
  const int hw = hw0 + hwl;
  const bool valid = hw < HW1;
  const int hwc = valid ? hw : HW1 - 1;
  const int ho = hwc / WO1, wo = hwc - ho * WO1;
  const int bb = blockIdx.y * NBB + wave * 16 + b2 * BJ;

  // ---- stage the block's full w slice: 108p x 16hw x 8o = 3456 float4 reads
  for (int i = t; i < 3456; i += 256) {
    const int o = i / 432, r = i - o * 432;
    const int p = r >> 2, q = r & 3;
    int hq = hw0 + q * 4;
    if (hq > HW1 - 4) hq = HW1 - 4;             // tail clamp (dup write, benign)
    const float4 wv =
        *reinterpret_cast<const float4*>(w1 + ((size_t)o * P1 + p) * HW1 + hq);
    const int base = p * 128 + (o >> 1) * 32 + (hq - hw0) * 2 + (o & 1);
    wl[base] = wv.x;
    wl[base + 2] = wv.y;
    wl[base + 4] = wv.z;
    wl[base + 6] = wv.w;
  }

  float acc[BJ][O1];
#pragma unroll
  for (int o = 0; o < O1; ++o) {
    const float bv = b1[o * HW1 + hwc];
#pragma unroll
    for (int j = 0; j < BJ; ++j) acc[j][o] = bv;
  }

  const float* xbase = x + (size_t)bb * IMG1 + (size_t)(ho * 4) * W1 + wo * 4;

  __syncthreads();                              // the ONLY barrier

  float xA[BJ][6], xB[BJ][6];

#define LC1_LD(K, XV)                                                          \
  do {                                                                         \
    const int c_ = (K) / 6, kh_ = (K) - c_ * 6;                                \
    const int xo_ = c_ * PLANE1 + kh_ * W1;                                    \
    _Pragma("unroll") for (int j = 0; j < BJ; ++j) {                           \
      const float* xr = xbase + (size_t)j * IMG1 + xo_;                        \
      const float2 a0 = *reinterpret_cast<const float2*>(xr);                  \
      const float2 a1 = *reinterpret_cast<const float2*>(xr + 2);              \
      const float2 a2 = *reinterpret_cast<const float2*>(xr + 4);              \
      XV[j][0] = a0.x; XV[j][1] = a0.y; XV[j][2] = a1.x;                       \
      XV[j][3] = a1.y; XV[j][4] = a2.x; XV[j][5] = a2.y;                       \
    }                                                                          \
  } while (0)

#define LC1_FMA(K, XV)                                                         \
  do {                                                                         \
    const float2* wb_ = reinterpret_cast<const float2*>(wl);                   \
    _Pragma("unroll") for (int kw = 0; kw < 6; ++kw) {                         \
      const int p_ = (K) * 6 + kw;                                             \
      const float2 w01 = wb_[p_ * 64 + hwl];                                   \
      const float2 w23 = wb_[p_ * 64 + 16 + hwl];                              \
      const float2 w45 = wb_[p_ * 64 + 32 + hwl];                              \
      const float2 w67 = wb_[p_ * 64 + 48 + hwl];                              \
      _Pragma("unroll") for (int j = 0; j < BJ; ++j) {                         \
        const float xs = XV[j][kw];                                            \
        acc[j][0] = fmaf(xs, w01.x, acc[j][0]);                                \
        acc[j][1] = fmaf(xs, w01.y, acc[j][1]);                                \
        acc[j][2] = fmaf(xs, w23.x, acc[j][2]);                                \
        acc[j][3] = fmaf(xs, w23.y, acc[j][3]);                                \
        acc[j][4] = fmaf(xs, w45.x, acc[j][4]);                                \
        acc[j][5] = fmaf(xs, w45.y, acc[j][5]);                                \
        acc[j][6] = fmaf(xs, w67.x, acc[j][6]);                                \
        acc[j][7] = fmaf(xs, w67.y, acc[j][7]);                                \
      }                                                                        \
    }                                                                          \
  } while (0)

  LC1_LD(0, xA);
#pragma unroll 1
  for (int k = 0; k < 18; k += 2) {
    LC1_LD(k + 1, xB);
    __builtin_amdgcn_sched_barrier(0);
    LC1_FMA(k, xA);
    if (k + 2 < 18) LC1_LD(k + 2, xA);
    __builtin_amdgcn_sched_barrier(0);
    LC1_FMA(k + 1, xB);
  }
#undef LC1_LD
#undef LC1_FMA

  if (valid) {
#pragma unroll
    for (int o = 0; o < O1; ++o) {
      const float4 v = make_float4(fmaxf(acc[0][o], 0.f), fmaxf(acc[1][o], 0.f),
                                   fmaxf(acc[2][o], 0.f), fmaxf(acc[3][o], 0.f));
      *reinterpret_cast<float4*>(h1t + ((size_t)o * HW1 + hw) * BATCH + bb) = v;
    }
  }
}

// ---- locally-connected layer 2 + ReLU, GEMM-ified per spatial location.
// h1t is batch-contiguous (O1,HW1,B) -> every x load is a coalesced 256B
// wave read (r12's (B,O,HW) gathers touched 64 lines/instr; ~610MB through
// L1 for a 19.5MB tensor - the hidden ~40-60us in rounds 2-12's totals).
__global__ __launch_bounds__(256) void lc2_kernel(const float* __restrict__ h1t,
                                                  const float* __restrict__ w2t,
                                                  const float* __restrict__ b2,
                                                  float* __restrict__ h2) {
  __shared__ float ws[P2 * O2];                 // 18432 B
  const int hw = blockIdx.x;
  const int lane = threadIdx.x & 63;
  const int og = threadIdx.x >> 6;
  const int b = blockIdx.y * 64 + lane;
  const int ho = hw / WO2, wo = hw - ho * WO2;

  for (int i = threadIdx.x; i < P2 * O2; i += 256) {
    const int p = i >> 4, o = i & 15;
    ws[i] = w2t[((size_t)p * HW2 + hw) * O2 + o];
  }
  __syncthreads();

  float acc[4];
#pragma unroll
  for (int oi = 0; oi < 4; ++oi) acc[oi] = b2[(og * 4 + oi) * HW2 + hw];

#pragma unroll 1
  for (int c = 0; c < C2; ++c) {
    // h1t index: channel c, row ho*4+kh, col wo*4+kw, batch b
    const float* bc =
        h1t + ((size_t)(c * H2c + ho * 4) * W2c + wo * 4) * BATCH + b;
    float xv[6][6];
#pragma unroll
    for (int kh = 0; kh < 6; ++kh)
#pragma unroll
      for (int kw = 0; kw < 6; ++kw)
        xv[kh][kw] = bc[(size_t)(kh * W2c + kw) * BATCH];
    __builtin_amdgcn_sched_barrier(0);
#pragma unroll
    for (int kh = 0; kh < 6; ++kh) {
#pragma unroll
      for (int kw = 0; kw < 6; ++kw) {
        const int p = (c * 6 + kh) * 6 + kw;
        const float4 wv = *reinterpret_cast<const float4*>(&ws[p * O2 + og * 4]);
        acc[0] = fmaf(xv[kh][kw], wv.x, acc[0]);
        acc[1] = fmaf(xv[kh][kw], wv.y, acc[1]);
        acc[2] = fmaf(xv[kh][kw], wv.z, acc[2]);
        acc[3] = fmaf(xv[kh][kw], wv.w, acc[3]);
      }
    }
  }

#pragma unroll
  for (int oi = 0; oi < 4; ++oi) {
    h2[((size_t)b * O2 + og * 4 + oi) * HW2 + hw] = fmaxf(acc[oi], 0.f);
  }
}

// ---- fused head: maxpool(2) -> FC1+ReLU -> FC2 -> softmax.
// one block (512 thr = 8 waves) per batch row; all intermediates in LDS.
__global__ __launch_bounds__(512) void head_kernel(const float* __restrict__ h2,
                                                   const float* __restrict__ fc1w,
                                                   const float* __restrict__ fc1b,
                                                   const float* __restrict__ fc2w,
                                                   const float* __restrict__ fc2b,
                                                   float* __restrict__ out) {
  __shared__ __align__(16) float sp[NPOOL];
  __shared__ __align__(16) float sh[N1];
  __shared__ float sl[N2];
  __shared__ float red[2];
  const int b = blockIdx.x;
  const int tid = threadIdx.x;

  if (tid < NPOOL) {
    const int o = tid / 30, r2 = tid - o * 30;
    const int i = r2 / 5, j = r2 - i * 5;
    const float* base = h2 + ((size_t)(b * O2 + o) * HO2 + 2 * i) * WO2 + 2 * j;
    sp[tid] = fmaxf(fmaxf(base[0], base[1]), fmaxf(base[WO2], base[WO2 + 1]));
  }
  __syncthreads();

  const int wv = tid >> 6, ln = tid & 63;
  const float4* sp4 = reinterpret_cast<const float4*>(sp);
  for (int n = wv; n < N1; n += 8) {
    const float4* wr = reinterpret_cast<const float4*>(fc1w + (size_t)n * NPOOL);
    float4 a = wr[ln], p = sp4[ln];
    float s = fmaf(a.x, p.x, fmaf(a.y, p.y, fmaf(a.z, p.z, a.w * p.w)));
    if (ln < 56) {
      float4 a2 = wr[64 + ln], p2 = sp4[64 + ln];
      s = fmaf(a2.x, p2.x, fmaf(a2.y, p2.y, fmaf(a2.z, p2.z, fmaf(a2.w, p2.w, s))));
    }
#pragma unroll
    for (int off = 32; off > 0; off >>= 1) s += __shfl_xor(s, off, 64);
    if (ln == 0) sh[n] = fmaxf(s + fc1b[n], 0.f);
  }
  __syncthreads();

  const float4* sh4 = reinterpret_cast<const float4*>(sh);
  for (int n = wv; n < N2; n += 8) {
    const float4* wr = reinterpret_cast<const float4*>(fc2w + (size_t)n * N1);
    float4 a = wr[ln], p = sh4[ln];
    float s = fmaf(a.x, p.x, fmaf(a.y, p.y, fmaf(a.z, p.z, a.w * p.w)));
    if (ln < 11) {
      float4 a2 = wr[64 + ln], p2 = sh4[64 + ln];
      s = fmaf(a2.x, p2.x, fmaf(a2.y, p2.y, fmaf(a2.z, p2.z, fmaf(a2.w, p2.w, s))));
    }
#pragma unroll
    for (int off = 32; off > 0; off >>= 1) s += __shfl_xor(s, off, 64);
    if (ln == 0) sl[n] = s + fc2b[n];
  }
  __syncthreads();

  if (wv == 0) {
    float m = fmaxf(fmaxf(sl[ln], sl[ln + 64]), sl[ln + 128]);
    if (ln < 8) m = fmaxf(m, sl[192 + ln]);
#pragma unroll
    for (int off = 32; off > 0; off >>= 1) m = fmaxf(m, __shfl_xor(m, off, 64));
    if (ln == 0) red[0] = m;
  }
  __syncthreads();
  const float mx = red[0];
  if (tid < N2) sl[tid] = expf(sl[tid] - mx);
  __syncthreads();
  if (wv == 0) {
    float s = sl[ln] + sl[ln + 64] + sl[ln + 128] + (ln < 8 ? sl[192 + ln] : 0.f);
#pragma unroll
    for (int off = 32; off > 0; off >>= 1) s += __shfl_xor(s, off, 64);
    if (ln == 0) red[1] = s;
  }
  __syncthreads();
  if (tid < N2) out[(size_t)b * N2 + tid] = sl[tid] / red[1];
}

}  // namespace

extern "C" void kernel_launch(void* const* d_in, const int* in_sizes, int n_in,
                              void* d_out, int out_size, void* d_ws, size_t ws_size,
                              hipStream_t stream) {
  const float* x     = (const float*)d_in[0];
  const float* w1    = (const float*)d_in[1];
  const float* b1    = (const float*)d_in[2];
  const float* w2    = (const float*)d_in[3];
  const float* b2    = (const float*)d_in[4];
  const float* fc1_w = (const float*)d_in[5];
  const float* fc1_b = (const float*)d_in[6];
  const float* fc2_w = (const float*)d_in[7];
  const float* fc2_b = (const float*)d_in[8];
  float* out = (float*)d_out;

  float* ws  = (float*)d_ws;
  float* w2t = ws;                                  //   599,040 f
  float* h1t = w2t + (size_t)O2 * P2 * HW2;         // 4,866,048 f  (O,HW,B)
  float* h2  = h1t + (size_t)BATCH * O1 * HW1;      //   532,480 f

  wt2_kernel<<<(P2 * HW2 + 255) / 256, 256, 0, stream>>>(w2, w2t);
  lc1_kernel<<<dim3((HW1 + THW - 1) / THW, BATCH / NBB), 256, 0, stream>>>(x, w1, b1, h1t);
  lc2_kernel<<<dim3(HW2, 4), 256, 0, stream>>>(h1t, w2t, b2, h2);
  head_kernel<<<BATCH, 512, 0, stream>>>(h2, fc1_w, fc1_b, fc2_w, fc2_b, out);
}